// Round 2
// baseline (1077.751 us; speedup 1.0000x reference)
//
#include <hip/hip_runtime.h>
#include <hip/hip_bf16.h>
#include <hip/hip_fp16.h>

#define T_DIM 8192
#define H_DIM 3200
#define I_DIM 12800

typedef int v4i __attribute__((ext_vector_type(4)));
typedef int v16i __attribute__((ext_vector_type(16)));
typedef _Float16 h8 __attribute__((ext_vector_type(8)));

__device__ __forceinline__ void gload16(const void* g, void* l) {
    __builtin_amdgcn_global_load_lds(
        (const __attribute__((address_space(1))) unsigned int*)g,
        (__attribute__((address_space(3))) unsigned int*)l, 16, 0, 0);
}

// ---------------- int32 -> int8 repack (memory-bound) ----------------
__global__ __launch_bounds__(256) void repack_kernel(const int* __restrict__ src,
                                                     unsigned int* __restrict__ dst,
                                                     long n4) {
    long i = (long)blockIdx.x * blockDim.x + threadIdx.x;
    long stride = (long)gridDim.x * blockDim.x;
    for (; i < n4; i += stride) {
        int4 v = ((const int4*)src)[i];
        dst[i] = (unsigned int)((v.x & 255) | ((v.y & 255) << 8) |
                                ((v.z & 255) << 16) | ((v.w & 255) << 24));
    }
}

// ---------------- i8 GEMM, C[M][N] = A[M][K] * B[N][K]^T ----------------
// 256x256 tile, 512 threads = 8 waves (2M x 4N), per-wave output 128x64 via
// mfma_i32_32x32x32_i8 (4m x 2n frags, 16 int acc each = 128 acc regs).
// Schedule: ONE phase per 64-byte K-half: {12 ds_read_b128 frags; stage A&B of
// half h+3 (4 gload16/thread); barrier; lgkmcnt(0); setprio1; 16 MFMA;
// setprio0; vmcnt(8); barrier}. Ring of 4 LDS slots per operand (4 x 16 KiB x
// 2 = 128 KiB). Counted gate: entering phase h, half h is resident and halves
// h+1,h+2 (8 loads) are in flight -- never drained to 0. LDS dest of
// global_load_lds is linear; the XOR swizzle (16B chunk cc ^= (row>>1)&3) is
// folded into the per-lane GLOBAL source (rule 21) and into ds_read addrs.
// 32-row frag read: lanes (L, L+32) read same row at chunks differing in bit0;
// per 8-row stripe all 8 bank-groups hit exactly 2x -> balanced, conflict-free.
// strideA/strideB in BYTES. EPI=0: fp16 out. EPI=1: fp32 of fp16-rounded.
// Bijective XCD swizzle on flattened block id (T1, m204 formula).
template <int EPI>
__global__ __launch_bounds__(512, 2) void gemm_i8_32x32(
    const signed char* __restrict__ A, long strideA,
    const signed char* __restrict__ B, long strideB,
    int Ntrue, int K, int ldc,
    const float* __restrict__ rowscale, const float* __restrict__ colscale,
    const float* __restrict__ bias, void* __restrict__ Cout) {
    __shared__ signed char lds[131072];
    signed char* ldsA = lds;           // 4 slots x 16384 B (256 rows x 64 B)
    signed char* ldsB = lds + 65536;   // 4 slots x 16384 B

    // T1: bijective XCD-aware remap of the flattened workgroup id.
    int bm, bn;
    {
        const int nwgx = gridDim.x;
        const int nwg = nwgx * gridDim.y;
        int id = blockIdx.x + nwgx * blockIdx.y;
        const int q = nwg >> 3, r = nwg & 7;
        const int x = id & 7, o = id >> 3;
        id = (x < r ? x * (q + 1) : r * (q + 1) + (x - r) * q) + o;
        bm = id % nwgx;
        bn = id / nwgx;
    }

    const int tid = threadIdx.x;
    const int lane = tid & 63, wid = tid >> 6;
    const int wr = wid >> 2, wc = wid & 3;
    const long Arow0 = (long)bm * 256;
    const long Bcol0 = (long)bn * 256;

    // Staging: slot = 256 rows x 64 B = 1024 chunks of 16 B; thread handles
    // chunks c0 = tid, c1 = tid+512. LDS dest linear; swizzle pre-applied to
    // the global source chunk.
    const int c0 = tid, c1 = tid + 512;
    const int r0 = c0 >> 2, r1_ = c1 >> 2;
    const int s0 = (((c0 & 3) ^ ((r0 >> 1) & 3)) << 4);
    const int s1 = (((c1 & 3) ^ ((r1_ >> 1) & 3)) << 4);
    const signed char* Ag0 = A + (Arow0 + r0) * strideA + s0;
    const signed char* Ag1 = A + (Arow0 + r1_) * strideA + s1;
    const signed char* Bg0 = B + (Bcol0 + r0) * strideB + s0;
    const signed char* Bg1 = B + (Bcol0 + r1_) * strideB + s1;
    const int d0 = c0 * 16, d1 = c1 * 16;

    const int NH = K >> 6;  // number of 64-byte K-halves (phases)

#define STAGE_A(h)                                  \
    {                                               \
        const int hc_ = (h) < NH ? (h) : NH - 1;    \
        const long ko_ = (long)hc_ << 6;            \
        signed char* d_ = ldsA + (((h) & 3) << 14); \
        gload16(Ag0 + ko_, d_ + d0);                \
        gload16(Ag1 + ko_, d_ + d1);                \
    }
#define STAGE_B(h)                                  \
    {                                               \
        const int hc_ = (h) < NH ? (h) : NH - 1;    \
        const long ko_ = (long)hc_ << 6;            \
        signed char* d_ = ldsB + (((h) & 3) << 14); \
        gload16(Bg0 + ko_, d_ + d0);                \
        gload16(Bg1 + ko_, d_ + d1);                \
    }

    // Fragment addressing (32x32x32 i8): lane reads 16 B at row (lane&31),
    // K-chunk sk*2 + (lane>>5) within the 64B row; swizzled chunk index
    // cc ^ ((row>>1)&3) reduces to a per-lane constant x0 (sk=0); sk=1 is ^32.
    const int rl = lane & 31, qh = lane >> 5;
    const int x0 = ((qh ^ ((rl >> 1) & 3)) << 4);
    const int aoff = (wr * 128 + rl) * 64 + x0;  // + m*2048 (m-tile = 32 rows)
    const int boff = (wc * 64 + rl) * 64 + x0;   // + n*2048

    v16i acc[4][2] = {};

    // Prologue: stage halves 0,1,2 (12 loads); gate to 8 -> half 0 resident,
    // halves 1,2 in flight (steady-state invariant entering phase 0).
    STAGE_A(0); STAGE_B(0); STAGE_A(1); STAGE_B(1); STAGE_A(2); STAGE_B(2);
    asm volatile("s_waitcnt vmcnt(8)");
    __builtin_amdgcn_s_barrier();

    for (int h = 0; h < NH; ++h) {
        const signed char* sA = ldsA + ((h & 3) << 14);
        const signed char* sB = ldsB + ((h & 3) << 14);
        v4i a0[4], a1[4], b0[2], b1[2];
#pragma unroll
        for (int m = 0; m < 4; ++m) {
            a0[m] = *(const v4i*)(sA + (aoff + m * 2048));
            a1[m] = *(const v4i*)(sA + ((aoff ^ 32) + m * 2048));
        }
#pragma unroll
        for (int n = 0; n < 2; ++n) {
            b0[n] = *(const v4i*)(sB + (boff + n * 2048));
            b1[n] = *(const v4i*)(sB + ((boff ^ 32) + n * 2048));
        }
        // stage half h+3 into slot (h+3)&3 = (h-1)&3 (its reads finished at
        // phase h-1; all waves barrier'd since).
        STAGE_A(h + 3);
        STAGE_B(h + 3);
        __builtin_amdgcn_s_barrier();
        asm volatile("s_waitcnt lgkmcnt(0)");
        __builtin_amdgcn_s_setprio(1);
#pragma unroll
        for (int m = 0; m < 4; ++m)
#pragma unroll
            for (int n = 0; n < 2; ++n)
                acc[m][n] = __builtin_amdgcn_mfma_i32_32x32x32_i8(
                    a0[m], b0[n], acc[m][n], 0, 0, 0);
#pragma unroll
        for (int m = 0; m < 4; ++m)
#pragma unroll
            for (int n = 0; n < 2; ++n)
                acc[m][n] = __builtin_amdgcn_mfma_i32_32x32x32_i8(
                    a1[m], b1[n], acc[m][n], 0, 0, 0);
        __builtin_amdgcn_s_setprio(0);
        // counted gate: retire the oldest unit-pair (half h+1); leave halves
        // h+2, h+3 (8 loads) in flight. Never 0 in the main loop.
        asm volatile("s_waitcnt vmcnt(8)");
        __builtin_amdgcn_s_barrier();
    }

    // Epilogue: 32x32 C/D layout col = lane&31, row = (reg&3)+8*(reg>>2)+4*qh.
    const int row0 = bm * 256 + wr * 128;
    const int col0 = bn * 256 + wc * 64;
    const int rbase = 4 * qh;
#pragma unroll
    for (int m = 0; m < 4; ++m) {
#pragma unroll
        for (int n = 0; n < 2; ++n) {
            const int col = col0 + n * 32 + rl;
            if (col < Ntrue) {
                const float cs = colscale[col];
                const float bs = bias[col];
#pragma unroll
                for (int g = 0; g < 4; ++g) {
#pragma unroll
                    for (int rr = 0; rr < 4; ++rr) {
                        const int row = row0 + m * 32 + rbase + 8 * g + rr;
                        float v = (float)acc[m][n][g * 4 + rr];
                        v = __fmul_rn(v, rowscale[row]);
                        v = __fmul_rn(v, cs);
                        v = __fadd_rn(v, bs);
                        _Float16 hh = (_Float16)v;  // reference rounds to fp16
                        const size_t idx = (size_t)row * ldc + col;
                        if (EPI == 0) ((_Float16*)Cout)[idx] = hh;
                        else ((float*)Cout)[idx] = (float)hh;
                    }
                }
            }
        }
    }
#undef STAGE_A
#undef STAGE_B
}

// -------- exact GELU + per-token dynamic int8 requant (in-place act_q) -------
__global__ __launch_bounds__(256) void gelu_quant(_Float16* __restrict__ fc1,
                                                  float* __restrict__ nscale) {
    __shared__ float gbuf[I_DIM];
    __shared__ float wmax[4];
    const int tid = threadIdx.x, lane = tid & 63, wid = tid >> 6;
    const long t = blockIdx.x;
    const h8* row = (const h8*)(fc1 + t * I_DIM);
    float lmax = 0.f;
    for (int c = tid; c < I_DIM / 8; c += 256) {
        h8 v = row[c];
#pragma unroll
        for (int j = 0; j < 8; ++j) {
            float x = (float)v[j];
            float e = erff(__fdiv_rn(x, 1.41421356237309504880f));
            float g = __fmul_rn(__fmul_rn(0.5f, x), __fadd_rn(1.0f, e));
            gbuf[c * 8 + j] = g;
            lmax = fmaxf(lmax, fabsf(g));
        }
    }
#pragma unroll
    for (int off = 32; off; off >>= 1) lmax = fmaxf(lmax, __shfl_xor(lmax, off, 64));
    if (lane == 0) wmax[wid] = lmax;
    __syncthreads();
    const float gmax = fmaxf(fmaxf(wmax[0], wmax[1]), fmaxf(wmax[2], wmax[3]));
    const float ns = gmax / 127.0f;
    if (tid == 0) nscale[t] = ns;
    unsigned long long* out = (unsigned long long*)(fc1 + t * I_DIM);  // in-place
    for (int c = tid; c < I_DIM / 8; c += 256) {
        unsigned long long pk = 0;
#pragma unroll
        for (int j = 0; j < 8; ++j) {
            float qv = rintf(__fdiv_rn(gbuf[c * 8 + j], ns));
            qv = fminf(fmaxf(qv, -127.f), 127.f);
            pk |= ((unsigned long long)(unsigned char)(signed char)(int)qv) << (8 * j);
        }
        out[c] = pk;
    }
}

extern "C" void kernel_launch(void* const* d_in, const int* in_sizes, int n_in,
                              void* d_out, int out_size, void* d_ws, size_t ws_size,
                              hipStream_t stream) {
    const int* hs = (const int*)d_in[0];        // [B,S,H] int8-in-int32
    const float* scale = (const float*)d_in[1]; // [T]
    const int* w1 = (const int*)d_in[2];        // [I,H]
    const float* w1s = (const float*)d_in[3];   // [I]
    const float* b1 = (const float*)d_in[4];    // [I]
    const int* w2 = (const int*)d_in[5];        // [H,I]
    const float* w2s = (const float*)d_in[6];   // [H]
    const float* b2 = (const float*)d_in[7];    // [H]

    char* ws = (char*)d_ws;
    signed char* xq = (signed char*)ws;                     // 26,214,400 B
    signed char* w1q = xq + (size_t)T_DIM * H_DIM;          // 40,960,000 B
    signed char* w2q = w1q + (size_t)I_DIM * H_DIM;         // 40,960,000 B
    _Float16* fc1h = (_Float16*)(w2q + (size_t)H_DIM * I_DIM);  // chunkT*I fp16
    const size_t fixed = (size_t)T_DIM * H_DIM + 2 * (size_t)I_DIM * H_DIM;

    // choose smallest chunk count whose workspace fits ws_size (deterministic)
    int nc = 1;
    while (nc < 16) {
        size_t need = fixed + ((size_t)T_DIM / nc) * I_DIM * 2 +
                      ((size_t)T_DIM / nc) * 4 + 256;
        if (need <= ws_size) break;
        nc <<= 1;
    }
    const int chunkT = T_DIM / nc;
    float* nscale = (float*)((char*)fc1h + (size_t)chunkT * I_DIM * 2);

    repack_kernel<<<2048, 256, 0, stream>>>(hs, (unsigned int*)xq, (long)T_DIM * H_DIM / 4);
    repack_kernel<<<2048, 256, 0, stream>>>(w1, (unsigned int*)w1q, (long)I_DIM * H_DIM / 4);
    repack_kernel<<<2048, 256, 0, stream>>>(w2, (unsigned int*)w2q, (long)H_DIM * I_DIM / 4);

    const int n2tiles = (H_DIM + 255) / 256;  // 13; last tile col-guarded
    for (int c = 0; c < nc; ++c) {
        const int t0 = c * chunkT;
        gemm_i8_32x32<0><<<dim3(chunkT / 256, I_DIM / 256), 512, 0, stream>>>(
            xq + (size_t)t0 * H_DIM, (long)H_DIM, w1q, (long)H_DIM,
            I_DIM, H_DIM, I_DIM,
            scale + t0, w1s, b1, (void*)fc1h);
        gelu_quant<<<chunkT, 256, 0, stream>>>(fc1h, nscale);
        gemm_i8_32x32<1><<<dim3(chunkT / 256, n2tiles), 512, 0, stream>>>(
            (const signed char*)fc1h, (long)I_DIM * 2, w2q, (long)I_DIM,
            H_DIM, I_DIM, H_DIM,
            nscale, w2s, b2,
            (void*)((float*)d_out + (size_t)t0 * H_DIM));
    }
}